// Round 1
// 149.615 us; speedup vs baseline: 1.0070x; 1.0070x over previous
//
#include <hip/hip_runtime.h>

typedef short v8s __attribute__((ext_vector_type(8)));
typedef float v4f __attribute__((ext_vector_type(4)));
typedef unsigned v4u __attribute__((ext_vector_type(4)));

#define Wh   1024
#define Hh   512
#define HWh  (Wh * Hh)
#define Wlr  512
#define HWlr (Wlr * 256)
#define PAD  136          // act row stride in shorts (272 B)
#define ITERS 8
#define NBLK  256         // 256 blocks x 16 waves x 8 iters x 16 px = 524288 px

// LDS layout (shorts):
//   wfrag[53*512]  : 53 fragments (W0:32, W1:16, W2:4, W3:1), lane-contiguous 16B frags
//   actS[16][16*PAD]: per-wave private activation buffer (layer outputs only now)
#define WFRAG_SHORTS (53 * 512)
#define ACT_SHORTS   (16 * PAD)
#define LDS_BYTES    ((WFRAG_SHORTS + 16 * ACT_SHORTS) * 2)   // 123904

__device__ __forceinline__ unsigned short f2bf(float f) {
    union { float f; unsigned u; } v; v.f = f;
    unsigned r = v.u + 0x7FFFu + ((v.u >> 16) & 1u);  // RNE (cold paths only)
    return (unsigned short)(r >> 16);
}
// hot-path pack: round-half-up bias + v_perm grabbing the two high halves (3 VALU)
__device__ __forceinline__ unsigned pk2(float a, float b) {
    union { float f; unsigned u; } ua, ub;
    ua.f = a; ub.f = b;
    return __builtin_amdgcn_perm(ub.u + 0x8000u, ua.u + 0x8000u, 0x07060302u);
}
__device__ __forceinline__ float leaky(float x) { return fmaxf(x, 0.01f * x); }

__global__ __launch_bounds__(1024, 4)
void cmfsm_kernel(const float* __restrict__ lr, const float* __restrict__ hr,
                  const float* __restrict__ w0g, const float* __restrict__ w1g,
                  const float* __restrict__ w2g, const float* __restrict__ w3g,
                  const float* __restrict__ w4g, const float* __restrict__ w5g,
                  const float* __restrict__ t0g, const float* __restrict__ t1g,
                  const float* __restrict__ t2g, const float* __restrict__ fwg,
                  float* __restrict__ out)
{
    extern __shared__ unsigned short smem[];
    unsigned short* wfrag = smem;                    // 53*512 shorts
    unsigned short* actS  = smem + WFRAG_SHORTS;

    const int tid  = threadIdx.x;
    const int lane = tid & 63;
    const int wv   = tid >> 6;
    const int p    = lane & 15;   // MFMA n (pixel)
    const int q    = lane >> 4;   // MFMA k-quad

    // ---- stage weights as A-fragments into LDS, fragment-major ----
    for (int e = tid; e < 32 * 64; e += 1024) {
        int f = e >> 6, l = e & 63;
        int mt = f >> 2, ks = f & 3, pp = l & 15, qq = l >> 4;
        const float* src = w0g + (mt * 16 + pp) * 128 + ks * 32 + qq * 8;
        unsigned short* dst = wfrag + f * 512 + l * 8;
#pragma unroll
        for (int j = 0; j < 8; ++j) dst[j] = f2bf(src[j]);
    }
    if (tid < 16 * 64) {
        int f = tid >> 6, l = tid & 63;
        int mt = f >> 2, ks = f & 3, pp = l & 15, qq = l >> 4;
        const float* src = w1g + (mt * 16 + pp) * 128 + ks * 32 + qq * 8;
        unsigned short* dst = wfrag + (32 + f) * 512 + l * 8;
#pragma unroll
        for (int j = 0; j < 8; ++j) dst[j] = f2bf(src[j]);
    }
    if (tid < 4 * 64) {
        int f = tid >> 6, l = tid & 63;
        int mt = f >> 1, ks = f & 1, pp = l & 15, qq = l >> 4;
        const float* src = w2g + (mt * 16 + pp) * 64 + ks * 32 + qq * 8;
        unsigned short* dst = wfrag + (48 + f) * 512 + l * 8;
#pragma unroll
        for (int j = 0; j < 8; ++j) dst[j] = f2bf(src[j]);
    }
    if (tid < 64) {
        int l = tid;
        int pp = l & 15, qq = l >> 4;
        const float* src = w3g + pp * 32 + qq * 8;
        unsigned short* dst = wfrag + 52 * 512 + l * 8;
#pragma unroll
        for (int j = 0; j < 8; ++j) dst[j] = f2bf(src[j]);
    }

    // ---- fused linear layers 4+5: w45[r] = sum_j w5[j]*w4[j][4q+r] ----
    float w45[4];
#pragma unroll
    for (int r = 0; r < 4; ++r) {
        float s = 0.f;
#pragma unroll
        for (int j = 0; j < 8; ++j) s += w5g[j] * w4g[j * 16 + q * 4 + r];
        w45[r] = s;
    }

    // ---- weights2: only 4 parity values ----
    float w2t0, w2t1, w2t2, w2t3;
    {
        float tab[4];
#pragma unroll
        for (int yp = 0; yp < 2; ++yp)
#pragma unroll
            for (int xp = 0; xp < 2; ++xp) {
                float i0 = xp ? 1.f : -1.f;
                float i1 = yp ? 1.f : -1.f;
                float i2 = 1.41421356237309505f;
                float h0[3], h1[2];
                for (int o = 0; o < 3; ++o)
                    h0[o] = leaky(t0g[o*3+0]*i0 + t0g[o*3+1]*i1 + t0g[o*3+2]*i2);
                for (int o = 0; o < 2; ++o)
                    h1[o] = leaky(t1g[o*3+0]*h0[0] + t1g[o*3+1]*h0[1] + t1g[o*3+2]*h0[2]);
                tab[yp*2+xp] = t2g[0]*h1[0] + t2g[1]*h1[1];
            }
        w2t0 = tab[0]; w2t1 = tab[1]; w2t2 = tab[2]; w2t3 = tab[3];
    }
    const float fa = fabsf(fwg[0]);
    const float fb = fabsf(fwg[1]);

    __syncthreads();   // wfrag ready; everything after is wave-private

    // hoisted LDS addresses (constant across iterations)
    unsigned short* Arow = actS + wv * ACT_SHORTS + p * PAD;  // act row for pixel p
    const unsigned short* ARq8 = Arow + q * 8;                // B-frag read base
    unsigned short* AWq4       = Arow + q * 4;                // C-pack write base
    const unsigned short* WL   = wfrag + lane * 8;            // A-frag read base

    // ---- per-lane per-channel global pointers: lane (q,p) owns ch = q*8+j ----
    // hr offset is linear in gbase: y*Wh + xg == gbase + p  (stride 256 px = 1024B/iter)
    // lr row index y>>1 == blockIdx.x for ALL 8 iters; col offset = (it&3)*128 floats
    const float* hrp[8];
    const float* lrp[8];
    {
        const int hbase = blockIdx.x * 2048 + wv * 16 + p;
        const int lbase = blockIdx.x * 512  + wv * 8  + (p >> 1);
#pragma unroll
        for (int j = 0; j < 8; ++j) {
            hrp[j] = hr + (size_t)(q * 8 + j) * HWh  + hbase;
            lrp[j] = lr + (size_t)(q * 8 + j) * HWlr + lbase;
        }
    }

    // ---- software pipeline: preload iteration 0's 16 staging values ----
    float h[8], l[8];
#pragma unroll
    for (int j = 0; j < 8; ++j) { h[j] = hrp[j][0]; l[j] = lrp[j][0]; }

#pragma unroll 1
    for (int t = 0; t < 2; ++t) {
#pragma unroll
        for (int s = 0; s < 4; ++s) {
            // ---- build layer-0 B fragments entirely in registers ----
            // B-frag(ks) element j = rep channel ks*32 + q*8 + j for pixel p:
            //   ks0 = lr_up, ks1 = hr, ks2 = lr*hr, ks3 = (lr-hr)^2
            v4u bf0, bf1, bf2, bf3;
#pragma unroll
            for (int u = 0; u < 4; ++u) {
                float l0 = l[2*u], l1 = l[2*u+1];
                float h0 = h[2*u], h1 = h[2*u+1];
                bf0[u] = pk2(l0, l1);
                bf1[u] = pk2(h0, h1);
                bf2[u] = pk2(l0 * h0, l1 * h1);
                float d0 = l0 - h0, d1 = l1 - h1;
                bf3[u] = pk2(d0 * d0, d1 * d1);
            }
            v8s b0 = __builtin_bit_cast(v8s, bf0);
            v8s b1 = __builtin_bit_cast(v8s, bf1);
            v8s b2 = __builtin_bit_cast(v8s, bf2);
            v8s b3 = __builtin_bit_cast(v8s, bf3);

            // ---- advance hr pointers (+256 px) and issue next iter's loads ----
#pragma unroll
            for (int j = 0; j < 8; ++j) hrp[j] += 256;
            if (t == 0 || s < 3) {                    // skip only very last prefetch
                const int nlr = ((s + 1) & 3) * 128;  // compile-time imm per unrolled s
#pragma unroll
                for (int j = 0; j < 8; ++j) {
                    h[j] = hrp[j][0];
                    l[j] = lrp[j][nlr];
                }
            }

            // ---- layer 0: 128 -> 128, two 4-mt halves (B stays in regs) ----
#pragma unroll
            for (int half = 0; half < 2; ++half) {
                v4f acc[4];
#pragma unroll
                for (int m2 = 0; m2 < 4; ++m2) acc[m2] = (v4f){0.f, 0.f, 0.f, 0.f};
#pragma unroll
                for (int ks = 0; ks < 4; ++ks) {
                    v8s b = (ks == 0) ? b0 : (ks == 1) ? b1 : (ks == 2) ? b2 : b3;
#pragma unroll
                    for (int m2 = 0; m2 < 4; ++m2) {
                        const int mt = half * 4 + m2;
                        v8s a = *(const v8s*)(WL + (mt * 4 + ks) * 512);
                        acc[m2] = __builtin_amdgcn_mfma_f32_16x16x32_bf16(a, b, acc[m2], 0, 0, 0);
                    }
                }
#pragma unroll
                for (int m2 = 0; m2 < 4; ++m2) {
                    const int mt = half * 4 + m2;
                    uint2 v;
                    v.x = pk2(leaky(acc[m2][0]), leaky(acc[m2][1]));
                    v.y = pk2(leaky(acc[m2][2]), leaky(acc[m2][3]));
                    *(uint2*)(AWq4 + mt * 16) = v;    // act[p][16mt+4q+r]
                }
            }

            // ---- layer 1: 128 -> 64 ----
            {
                v4f acc1[4];
#pragma unroll
                for (int mt = 0; mt < 4; ++mt) acc1[mt] = (v4f){0.f, 0.f, 0.f, 0.f};
#pragma unroll
                for (int ks = 0; ks < 4; ++ks) {
                    v8s b = *(const v8s*)(ARq8 + ks * 32);
#pragma unroll
                    for (int mt = 0; mt < 4; ++mt) {
                        v8s a = *(const v8s*)(WL + (32 + mt * 4 + ks) * 512);
                        acc1[mt] = __builtin_amdgcn_mfma_f32_16x16x32_bf16(a, b, acc1[mt], 0, 0, 0);
                    }
                }
#pragma unroll
                for (int mt = 0; mt < 4; ++mt) {
                    uint2 v;
                    v.x = pk2(leaky(acc1[mt][0]), leaky(acc1[mt][1]));
                    v.y = pk2(leaky(acc1[mt][2]), leaky(acc1[mt][3]));
                    *(uint2*)(AWq4 + mt * 16) = v;
                }
            }

            // ---- layer 2: 64 -> 32 ----
            {
                v4f acc2[2];
#pragma unroll
                for (int mt = 0; mt < 2; ++mt) acc2[mt] = (v4f){0.f, 0.f, 0.f, 0.f};
#pragma unroll
                for (int ks = 0; ks < 2; ++ks) {
                    v8s b = *(const v8s*)(ARq8 + ks * 32);
#pragma unroll
                    for (int mt = 0; mt < 2; ++mt) {
                        v8s a = *(const v8s*)(WL + (48 + mt * 2 + ks) * 512);
                        acc2[mt] = __builtin_amdgcn_mfma_f32_16x16x32_bf16(a, b, acc2[mt], 0, 0, 0);
                    }
                }
#pragma unroll
                for (int mt = 0; mt < 2; ++mt) {
                    uint2 v;
                    v.x = pk2(leaky(acc2[mt][0]), leaky(acc2[mt][1]));
                    v.y = pk2(leaky(acc2[mt][2]), leaky(acc2[mt][3]));
                    *(uint2*)(AWq4 + mt * 16) = v;
                }
            }

            // ---- layer 3: 32 -> 16, fused 16->8->1, fuse with weights2 ----
            {
                v8s b = *(const v8s*)(ARq8);
                v8s a = *(const v8s*)(WL + 52 * 512);
                v4f acc3 = __builtin_amdgcn_mfma_f32_16x16x32_bf16(a, b, (v4f){0.f, 0.f, 0.f, 0.f}, 0, 0, 0);

                float part = 0.f;
#pragma unroll
                for (int r = 0; r < 4; ++r) part += w45[r] * leaky(acc3[r]);
                part += __shfl_xor(part, 16, 64);
                part += __shfl_xor(part, 32, 64);

                if (q == 0) {
                    // y&1 == t, xg&1 == p&1; linear out index == gbase + p
                    const float w2v = t ? ((p & 1) ? w2t3 : w2t2)
                                        : ((p & 1) ? w2t1 : w2t0);
                    const int gidx = blockIdx.x * 2048 + (t * 4 + s) * 256 + wv * 16 + p;
                    out[gidx] = fa * part + fb * w2v;
                }
            }
        }
    }
}

extern "C" void kernel_launch(void* const* d_in, const int* in_sizes, int n_in,
                              void* d_out, int out_size, void* d_ws, size_t ws_size,
                              hipStream_t stream) {
    const float* lr  = (const float*)d_in[0];
    const float* hr  = (const float*)d_in[1];
    const float* w0g = (const float*)d_in[2];
    const float* w1g = (const float*)d_in[3];
    const float* w2g = (const float*)d_in[4];
    const float* w3g = (const float*)d_in[5];
    const float* w4g = (const float*)d_in[6];
    const float* w5g = (const float*)d_in[7];
    const float* t0g = (const float*)d_in[8];
    const float* t1g = (const float*)d_in[9];
    const float* t2g = (const float*)d_in[10];
    const float* fwg = (const float*)d_in[11];
    float* out = (float*)d_out;

    hipLaunchKernelGGL(cmfsm_kernel, dim3(NBLK), dim3(1024), LDS_BYTES, stream,
                       lr, hr, w0g, w1g, w2g, w3g, w4g, w5g, t0g, t1g, t2g, fwg, out);
}